// Round 11
// baseline (406.435 us; speedup 1.0000x reference)
//
#include <hip/hip_runtime.h>
#include <hip/hip_bf16.h>

typedef unsigned short u16;
typedef _Float16 h16;
typedef h16 h16x8 __attribute__((ext_vector_type(8)));
typedef h16 h16x4 __attribute__((ext_vector_type(4)));
typedef float f32x4 __attribute__((ext_vector_type(4)));

#define S_LEN 2048
#define QLR   1536
#define KVLR  512
#define NHEAD 16
#define QHD   192
#define QHS   200   // padded row stride for Qh/Kh
#define VDIM  128
#define SCALE 0.07216878364870322f   // 192^-0.5
#define FREQC (-0.4152410118609203f) // -log2(10000)/32

__device__ __forceinline__ void gld16(const h16* g, h16* l){
  __builtin_amdgcn_global_load_lds((__attribute__((address_space(1))) const void*)g,
                                   (__attribute__((address_space(3))) void*)l, 16, 0, 0);
}

// ---------- merged preprocessing: fp32->fp16 cvt + 5 weight transposes ----------
__global__ __launch_bounds__(256) void k_prep(const float* __restrict__ hidden, h16* __restrict__ hb,
      const float* __restrict__ Wqa, const float* __restrict__ Wkva, const float* __restrict__ Wqb,
      const float* __restrict__ Wkvb, const float* __restrict__ Wo,
      h16* __restrict__ Wc, h16* __restrict__ WqbT, h16* __restrict__ WkvbT, h16* __restrict__ WoT){
  int bx = blockIdx.x;
  const int tid = threadIdx.x;
  if (bx < 4096){
    int i = bx*256 + tid;
    float4 v = ((const float4*)hidden)[i];
    h16x4 o = { (h16)v.x, (h16)v.y, (h16)v.z, (h16)v.w };
    ((h16x4*)hb)[i] = o;
    return;
  }
  bx -= 4096;
  const float* W; h16* WT; int K, N, nx;
  if (bx < 768)       { W = Wqa;  WT = Wc;                K = 2048; N = 1536; nx = 24; }
  else if (bx < 1056) { bx -= 768;  W = Wkva; WT = Wc + 1536ull*2048; K = 2048; N = 576;  nx = 9;  }
  else if (bx < 2208) { bx -= 1056; W = Wqb;  WT = WqbT;  K = 1536; N = 3072; nx = 48; }
  else if (bx < 2720) { bx -= 2208; W = Wkvb; WT = WkvbT; K = 512;  N = 4096; nx = 64; }
  else                { bx -= 2720; W = Wo;   WT = WoT;   K = 2048; N = 2048; nx = 32; }
  int ty = bx / nx, tx = bx - ty*nx;
  int k0 = ty * 64, n0 = tx * 64;
  __shared__ float t[64][65];
  int r = tid >> 4, c4 = (tid & 15) * 4;
#pragma unroll
  for (int it = 0; it < 4; it++){
    float4 v = *(const float4*)(W + (size_t)(k0 + it*16 + r) * N + n0 + c4);
    t[it*16+r][c4] = v.x; t[it*16+r][c4+1] = v.y; t[it*16+r][c4+2] = v.z; t[it*16+r][c4+3] = v.w;
  }
  __syncthreads();
  int n = tid >> 2, k16 = (tid & 3) * 16;
  h16x8 o0, o1;
#pragma unroll
  for (int e = 0; e < 8; e++){ o0[e] = (h16)t[k16 + e][n]; o1[e] = (h16)t[k16 + 8 + e][n]; }
  h16* dst = WT + (size_t)(n0 + n) * K + k0 + k16;
  *(h16x8*)dst = o0;
  *(h16x8*)(dst + 8) = o1;
}

// ---------- shared GEMM mainloop (MB = 64 or 128 row tile) ----------
template<int MB>
__device__ __forceinline__ void gemm_coreT(const h16* __restrict__ A, const h16* __restrict__ B,
    int K, int m0, int n0, h16* As, h16* Bs, f32x4 (&acc)[MB/32][4]){
  const int tid = threadIdx.x;
  const int lane = tid & 63, quad = lane >> 4, lr = lane & 15;
  const int wid = tid >> 6;
  const int wr = (wid >> 1) * (MB/2), wc = (wid & 1) * 64;
  const int sr = tid >> 2, scc = (tid & 3) * 8;
  const h16* Ag = A + (size_t)(m0 + sr) * K + scc;
  const h16* Bg = B + (size_t)(n0 + sr) * K + scc;
  for (int kt = 0; kt < K; kt += 32){
    gld16(Ag + kt, &As[tid * 8]);
    if (MB == 128) gld16(Ag + (size_t)64*K + kt, &As[2048 + tid * 8]);
    gld16(Bg + kt,                 &Bs[tid * 8]);
    gld16(Bg + (size_t)64*K + kt,  &Bs[2048 + tid * 8]);
    __syncthreads();
    h16x8 af[MB/32], bfr[4];
#pragma unroll
    for (int r = 0; r < MB/32; r++) af[r] = *(const h16x8*)&As[(wr + r*16 + lr) * 32 + quad * 8];
#pragma unroll
    for (int c = 0; c < 4; c++) bfr[c] = *(const h16x8*)&Bs[(wc + c*16 + lr) * 32 + quad * 8];
#pragma unroll
    for (int r = 0; r < MB/32; r++)
#pragma unroll
      for (int c = 0; c < 4; c++)
        acc[r][c] = __builtin_amdgcn_mfma_f32_16x16x32_f16(af[r], bfr[c], acc[r][c], 0, 0, 0);
    __syncthreads();
  }
}

// ---------- plain GEMM ----------
template<bool OF32, int MB>
__global__ __launch_bounds__(256) void k_gemm(const h16* __restrict__ A, const h16* __restrict__ B,
                                              void* __restrict__ Cv, int N, int K){
  __shared__ __attribute__((aligned(16))) h16 As[MB*32];
  __shared__ __attribute__((aligned(16))) h16 Bs[128*32];
  const int m0 = blockIdx.y * MB, n0 = blockIdx.x * 128;
  f32x4 acc[MB/32][4] = {};
  gemm_coreT<MB>(A, B, K, m0, n0, As, Bs, acc);
  const int lane = threadIdx.x & 63, quad = lane >> 4, lr = lane & 15;
  const int wid = threadIdx.x >> 6;
  const int wr = (wid >> 1) * (MB/2), wc = (wid & 1) * 64;
#pragma unroll
  for (int r = 0; r < MB/32; r++)
#pragma unroll
    for (int c = 0; c < 4; c++){
      int row = m0 + wr + r*16 + quad*4;
      int col = n0 + wc + c*16 + lr;
#pragma unroll
      for (int i = 0; i < 4; i++){
        float val = acc[r][c][i];
        if (OF32) ((float*)Cv)[(size_t)(row + i) * N + col] = val;
        else      ((h16*)Cv)[(size_t)(row + i) * N + col] = (h16)val;
      }
    }
}

// ---------- merged Q + KV GEMM (union LDS: tsm aliases As/Bs) ----------
__global__ __launch_bounds__(256) void k_gemm_qkv(const h16* __restrict__ qln, const h16* __restrict__ WqbT,
      const h16* __restrict__ kvln, const h16* __restrict__ WkvbT,
      h16* __restrict__ Qh, h16* __restrict__ Kh, h16* __restrict__ VT,
      const float* __restrict__ cst, const float* __restrict__ snt){
  __shared__ __attribute__((aligned(16))) h16 smem[16896];   // 33792 B: max(As+Bs, tsm)
  h16* As = smem;
  h16* Bs = smem + 4096;
  const int m0 = blockIdx.y * 128;
  const int tid = threadIdx.x;
  const int lane = tid & 63, quad = lane >> 4, lr = lane & 15;
  const int wid = tid >> 6;
  const int wr = (wid >> 1) * 64, wc = (wid & 1) * 64;
  f32x4 acc[4][4] = {};
  if (blockIdx.x < 24){
    // ---- Q path: qln x WqbT with scale/RoPE epilogue -> Qh (stride 200) ----
    const int n0 = blockIdx.x * 128;
    gemm_coreT<128>(qln, WqbT, QLR, m0, n0, As, Bs, acc);
#pragma unroll
    for (int r = 0; r < 4; r++)
#pragma unroll
      for (int c = 0; c < 4; c++){
        int row0 = m0 + wr + r*16 + quad*4;
        int cg = n0 + wc + c*16 + lr;
        int head = cg / 192;
        int inner = cg - head*192;
        h16* outb = Qh + ((size_t)head*S_LEN)*QHS;
        if (inner < 128){
#pragma unroll
          for (int i = 0; i < 4; i++)
            outb[(size_t)(row0+i)*QHS + inner] = (h16)(acc[r][c][i] * SCALE);
        } else {
          int d = (inner - 128) >> 1;
          int isY = inner & 1;
          int ocol = (isY ? 160 : 128) + d;
#pragma unroll
          for (int i = 0; i < 4; i++){
            int rr = row0 + i;
            float cs = cst[rr*32 + d], sn = snt[rr*32 + d];
            float v = acc[r][c][i];
            float w = __shfl_xor(v, 1);
            float out = isY ? (v*cs + w*sn) : (v*cs - w*sn);
            outb[(size_t)rr*QHS + ocol] = (h16)(out * SCALE);
          }
        }
      }
  } else {
    // ---- KV path: kvln x WkvbT -> Kh nope (stride 200) / VT (rotated, transposed-store) ----
    const int n0 = (blockIdx.x - 24) * 128;
    gemm_coreT<128>(kvln, WkvbT, KVLR, m0, n0, As, Bs, acc);
    const int head = n0 >> 8;
    if ((n0 & 128) == 0){
#pragma unroll
      for (int r = 0; r < 4; r++)
#pragma unroll
        for (int c = 0; c < 4; c++){
          int row0 = m0 + wr + r*16 + quad*4;
          int inner = wc + c*16 + lr;
#pragma unroll
          for (int i = 0; i < 4; i++)
            Kh[((size_t)head*S_LEN + row0 + i)*QHS + inner] = (h16)acc[r][c][i];
        }
    } else {
      // store TRANSPOSED into tsm[dv][row] (stride 132) with h16x4 vector writes
      h16* tsm = smem;   // aliases As/Bs (dead after gemm_coreT's final barrier)
#pragma unroll
      for (int r = 0; r < 4; r++)
#pragma unroll
        for (int c = 0; c < 4; c++){
          int dv = wc + c*16 + lr;
          int row0 = wr + r*16 + quad*4;
          h16x4 o = { (h16)acc[r][c][0], (h16)acc[r][c][1], (h16)acc[r][c][2], (h16)acc[r][c][3] };
          *(h16x4*)&tsm[dv*132 + row0] = o;
        }
      __syncthreads();
      int dv = tid >> 1, half = tid & 1;
      h16* vout = VT + ((size_t)(head*VDIM + dv))*S_LEN + m0 + half*64;
#pragma unroll
      for (int k = 0; k < 8; k++){
        h16x4 a = *(const h16x4*)&tsm[dv*132 + half*64 + k*8];
        h16x4 b = *(const h16x4*)&tsm[dv*132 + half*64 + k*8 + 4];
        h16x8 v = { a[0],a[1],a[2],a[3], b[0],b[1],b[2],b[3] };
        *(h16x8*)(vout + ((k*8 + 8*(dv & 7)) & 63)) = v;
      }
    }
  }
}

// ---------- RMSNorm + k_pe RoPE (writes Kh rope cols for all heads) + cos/sin tables ----------
__global__ __launch_bounds__(256) void k_norm(const h16* __restrict__ Cc,
      const float* __restrict__ qw, const float* __restrict__ kw, const int* __restrict__ pos_ids,
      h16* __restrict__ qln, h16* __restrict__ kvln, h16* __restrict__ Kh,
      float* __restrict__ cst, float* __restrict__ snt){
  const int s = blockIdx.x, tid = threadIdx.x;
  __shared__ float red[8];
  __shared__ h16 kpe_s[64];
  const h16* c1 = Cc + (size_t)s * 2176;
  float v[6]; float ss = 0.f;
#pragma unroll
  for (int i = 0; i < 6; i++){ v[i] = (float)c1[tid + i*256]; ss += v[i]*v[i]; }
  for (int off = 32; off > 0; off >>= 1) ss += __shfl_down(ss, off);
  if ((tid & 63) == 0) red[tid >> 6] = ss;
  __syncthreads();
  float rq = rsqrtf((red[0]+red[1]+red[2]+red[3]) / (float)QLR + 1e-6f);
#pragma unroll
  for (int i = 0; i < 6; i++)
    qln[(size_t)s * QLR + tid + i*256] = (h16)(qw[tid + i*256] * v[i] * rq);

  const h16* ck = c1 + QLR;
  float w0 = (float)ck[tid], w1 = (float)ck[tid + 256];
  float ss2 = w0*w0 + w1*w1;
  for (int off = 32; off > 0; off >>= 1) ss2 += __shfl_down(ss2, off);
  if ((tid & 63) == 0) red[4 + (tid >> 6)] = ss2;
  __syncthreads();
  float rk = rsqrtf((red[4]+red[5]+red[6]+red[7]) / (float)KVLR + 1e-6f);
  kvln[(size_t)s * KVLR + tid]       = (h16)(kw[tid] * w0 * rk);
  kvln[(size_t)s * KVLR + tid + 256] = (h16)(kw[tid + 256] * w1 * rk);

  if (tid < 32){
    int d = tid;
    float x = (float)ck[KVLR + 2*d];
    float y = (float)ck[KVLR + 2*d + 1];
    float a = (float)pos_ids[s] * exp2f(FREQC * (float)d);
    float cs = cosf(a), sn = sinf(a);
    cst[s*32 + d] = cs; snt[s*32 + d] = sn;
    kpe_s[d]      = (h16)(x*cs - y*sn);
    kpe_s[32 + d] = (h16)(y*cs + x*sn);
  }
  __syncthreads();
  {
    int h = tid >> 4, seg = (tid & 15) * 4;
    h16x4 o = { kpe_s[seg], kpe_s[seg+1], kpe_s[seg+2], kpe_s[seg+3] };
    *(h16x4*)&Kh[((size_t)h*S_LEN + s)*QHS + 128 + seg] = o;
  }
}

// ---------- causal flash (r7 form + chunked P): BM=128, BKV=64, split-KV <=8, 3 blocks/CU ----------
__global__ __launch_bounds__(256, 3) void k_flash(const h16* __restrict__ Qh, const h16* __restrict__ Kh,
      const h16* __restrict__ VT, h16* __restrict__ Opart, float* __restrict__ ml){
  const int tile = 15 - blockIdx.x;   // most work first
  const int h = blockIdx.y;
  const int p = blockIdx.z;
  const int jcount = 2*tile + 2;
  const int jlo = p * 8;
  if (jlo >= jcount) return;
  const int jhi = min(jlo + 8, jcount);
  const int m0 = tile * 128;
  __shared__ __attribute__((aligned(16))) h16 Ksm[64*QHS];   // 25600 B
  __shared__ __attribute__((aligned(16))) h16 Vsm[144*64];   // 18432 B, rows 128..143 = ones
  __shared__ __attribute__((aligned(16))) h16 Psm[128*36];   // 9216 B: [128 q][32 kv-chunk + 4 pad]
  const int tid = threadIdx.x, wid = tid >> 6, lane = tid & 63, quad = lane >> 4, lr = lane & 15;

  {
    h16x4 one4 = { (h16)1.f, (h16)1.f, (h16)1.f, (h16)1.f };
    *(h16x4*)&Vsm[128*64 + tid*4] = one4;
  }

  // Q fragments direct from global (once per block)
  const h16* Qbase = Qh + ((size_t)h*S_LEN + m0)*QHS;
  h16x8 qf[2][6];
#pragma unroll
  for (int rt = 0; rt < 2; rt++)
#pragma unroll
    for (int ks = 0; ks < 6; ks++)
      qf[rt][ks] = *(const h16x8*)(Qbase + (size_t)(wid*32 + rt*16 + lr)*QHS + ks*32 + quad*8);

  float mst[2][4];
  f32x4 oacc[2][9] = {};   // 8 V tiles + 1 ones tile (row-sum l)
#pragma unroll
  for (int rt = 0; rt < 2; rt++)
#pragma unroll
    for (int i = 0; i < 4; i++) mst[rt][i] = -1e30f;

  for (int j = jlo; j < jhi; ++j){
    const h16* Kg = Kh + ((size_t)h*S_LEN + j*64)*QHS;
#pragma unroll
    for (int i = 0; i < 6; i++) gld16(Kg + i*2048 + tid*8, &Ksm[i*2048 + tid*8]);
    if (tid < 64) gld16(Kg + 12288 + tid*8, &Ksm[12288 + tid*8]);
    const h16* Vg = VT + (size_t)h * VDIM * S_LEN + (size_t)j * 64;
#pragma unroll
    for (int i = 0; i < 4; i++)
      gld16(Vg + (size_t)(i*32 + (tid >> 3)) * S_LEN + (tid & 7)*8, &Vsm[i*2048 + tid*8]);
    __syncthreads();

    f32x4 sc[2][4] = {};
#pragma unroll
    for (int ks = 0; ks < 6; ks++)
#pragma unroll
      for (int ct = 0; ct < 4; ct++){
        h16x8 kf = *(const h16x8*)&Ksm[(ct*16 + lr)*QHS + ks*32 + quad*8];
        sc[0][ct] = __builtin_amdgcn_mfma_f32_16x16x32_f16(qf[0][ks], kf, sc[0][ct], 0,0,0);
        sc[1][ct] = __builtin_amdgcn_mfma_f32_16x16x32_f16(qf[1][ks], kf, sc[1][ct], 0,0,0);
      }

    if (j >= 2*tile){
#pragma unroll
      for (int rt = 0; rt < 2; rt++)
#pragma unroll
        for (int ct = 0; ct < 4; ct++){
          int kcol = j*64 + ct*16 + lr;
#pragma unroll
          for (int i = 0; i < 4; i++)
            if (kcol > m0 + wid*32 + rt*16 + quad*4 + i) sc[rt][ct][i] = -1e30f;
        }
    }

#pragma unroll
    for (int rt = 0; rt < 2; rt++){
      float al[4];
#pragma unroll
      for (int i = 0; i < 4; i++){
        float m = fmaxf(fmaxf(sc[rt][0][i], sc[rt][1][i]), fmaxf(sc[rt][2][i], sc[rt][3][i]));
#pragma unroll
        for (int off = 1; off < 16; off <<= 1) m = fmaxf(m, __shfl_xor(m, off));
        // floor guard: fully-masked rows must yield P=0, not exp(0)=1
        float mn = fmaxf(fmaxf(mst[rt][i], m), -1e29f);
        al[i] = __expf(mst[rt][i] - mn);
        mst[rt][i] = mn;
      }
#pragma unroll
      for (int oc = 0; oc < 9; oc++)
#pragma unroll
        for (int i = 0; i < 4; i++) oacc[rt][oc][i] *= al[i];
    }

    // PV in two 32-kv chunks through small Psm (per-wave rows; in-order DS pipe, no barrier)
#pragma unroll
    for (int c2 = 0; c2 < 2; c2++){
#pragma unroll
      for (int rt = 0; rt < 2; rt++)
#pragma unroll
        for (int cc = 0; cc < 2; cc++){
          int ct = c2*2 + cc;
#pragma unroll
          for (int i = 0; i < 4; i++)
            Psm[(wid*32 + rt*16 + quad*4 + i)*36 + cc*16 + lr] = (h16)__expf(sc[rt][ct][i] - mst[rt][i]);
        }
      h16x8 pf0 = *(const h16x8*)&Psm[(wid*32 + lr)*36      + quad*8];
      h16x8 pf1 = *(const h16x8*)&Psm[(wid*32 + 16 + lr)*36 + quad*8];
      int cv = (c2*32 + quad*8 + 8*(lr & 7)) & 63;
#pragma unroll
      for (int oc = 0; oc < 9; oc++){
        h16x8 vf = *(const h16x8*)&Vsm[(oc*16 + lr)*64 + cv];
        oacc[0][oc] = __builtin_amdgcn_mfma_f32_16x16x32_f16(pf0, vf, oacc[0][oc], 0,0,0);
        oacc[1][oc] = __builtin_amdgcn_mfma_f32_16x16x32_f16(pf1, vf, oacc[1][oc], 0,0,0);
      }
    }
    __syncthreads();
  }

  const int part = (tile*NHEAD + h)*4 + p;
  h16* Op = Opart + (size_t)part * 16384;
#pragma unroll
  for (int rt = 0; rt < 2; rt++){
#pragma unroll
    for (int oc = 0; oc < 8; oc++)
#pragma unroll
      for (int i = 0; i < 4; i++)
        Op[(wid*32 + rt*16 + quad*4 + i)*128 + oc*16 + lr] = (h16)oacc[rt][oc][i];
    if (lr == 0){
#pragma unroll
      for (int i = 0; i < 4; i++){
        int r = wid*32 + rt*16 + quad*4 + i;
        ml[(size_t)part*256 + r*2]     = mst[rt][i];
        ml[(size_t)part*256 + r*2 + 1] = oacc[rt][8][i];
      }
    }
  }
}

// ---------- LSE-combine partials -> Ob ----------
__global__ __launch_bounds__(256) void k_comb(const h16* __restrict__ Opart, const float* __restrict__ ml,
                                              h16* __restrict__ Ob){
  const int t = blockIdx.x, h = blockIdx.y, tid = threadIdx.x;
  const int P = (2*t + 9) >> 3;   // ceil((2t+2)/8)
  const int r = tid >> 1, c0 = (tid & 1) * 64;
  const int base = (t*NHEAD + h)*4;
  float w[4]; float M = -1e30f, denom = 0.f;
  for (int p = 0; p < P; p++) M = fmaxf(M, ml[(size_t)(base+p)*256 + r*2]);
  for (int p = 0; p < P; p++){
    w[p] = __expf(ml[(size_t)(base+p)*256 + r*2] - M);
    denom += w[p] * ml[(size_t)(base+p)*256 + r*2 + 1];
  }
  float inv = 1.f / denom;
#pragma unroll
  for (int ch = 0; ch < 8; ch++){
    float a[8] = {};
    for (int p = 0; p < P; p++){
      h16x8 v = *(const h16x8*)&Opart[(size_t)(base+p)*16384 + r*128 + c0 + ch*8];
#pragma unroll
      for (int e = 0; e < 8; e++) a[e] += w[p] * (float)v[e];
    }
    h16x8 o;
#pragma unroll
    for (int e = 0; e < 8; e++) o[e] = (h16)(a[e] * inv);
    *(h16x8*)&Ob[((size_t)(t*128 + r))*(NHEAD*VDIM) + h*VDIM + c0 + ch*8] = o;
  }
}

extern "C" void kernel_launch(void* const* d_in, const int* in_sizes, int n_in,
                              void* d_out, int out_size, void* d_ws, size_t ws_size,
                              hipStream_t stream){
  const float* hidden = (const float*)d_in[0];
  const int*   pos    = (const int*)  d_in[1];
  const float* Wqa    = (const float*)d_in[2];
  const float* qaw    = (const float*)d_in[3];
  const float* Wqb    = (const float*)d_in[4];
  const float* Wkva   = (const float*)d_in[5];
  const float* kvw    = (const float*)d_in[6];
  const float* Wkvb   = (const float*)d_in[7];
  const float* Wo     = (const float*)d_in[8];

  h16* ws = (h16*)d_ws;
  size_t off = 0;
  auto take = [&](size_t n){ h16* p = ws + off; off += n; return p; };
  h16* hb    = take(2048ull * 2048);
  h16* WoT   = take(2048ull * 2048);
  h16* Wc    = take(2176ull * 2048);   // alias region start (dead before flash)
  h16* WqbT  = take(3072ull * 1536);
  h16* WkvbT = take(4096ull * 512);
  h16* Ccomb = take(2048ull * 2176);
  h16* qln   = take(2048ull * 1536);
  h16* kvln  = take(2048ull * 512);    // alias region end
  float* cst = (float*)take(2048ull * 64);
  float* snt = (float*)take(2048ull * 64);
  h16* Qh    = take(16ull * 2048 * QHS);
  h16* Kh    = take(16ull * 2048 * QHS);
  h16* VT    = take(16ull * 128 * 2048);
  h16* Ob    = hb;                      // hb dead after Ccomb GEMM
  h16*   Opart = Wc;                    // 16*16*4*16384 h16 = 33.6 MB within 39.8 MB region
  float* mlbuf = (float*)(Wc + 16ull*16*4*16384);  // +0.5 MB, inside dead region

  k_prep<<<7840, 256, 0, stream>>>(hidden, hb, Wqa, Wkva, Wqb, Wkvb, Wo, Wc, WqbT, WkvbT, WoT);
  k_gemm<false,64><<<dim3(17, 32), 256, 0, stream>>>(hb, Wc, Ccomb, 2176, 2048);
  k_norm<<<2048, 256, 0, stream>>>(Ccomb, qaw, kvw, pos, qln, kvln, Kh, cst, snt);
  k_gemm_qkv<<<dim3(56, 16), 256, 0, stream>>>(qln, WqbT, kvln, WkvbT, Qh, Kh, VT, cst, snt);
  k_flash<<<dim3(16, 16, 4), 256, 0, stream>>>(Qh, Kh, VT, Opart, mlbuf);
  k_comb<<<dim3(16, 16), 256, 0, stream>>>(Opart, mlbuf, Ob);
  k_gemm<true,64><<<dim3(16, 32), 256, 0, stream>>>(Ob, WoT, d_out, 2048, 2048);
}

// Round 12
// 362.522 us; speedup vs baseline: 1.1211x; 1.1211x over previous
//
#include <hip/hip_runtime.h>
#include <hip/hip_bf16.h>

typedef unsigned short u16;
typedef _Float16 h16;
typedef h16 h16x8 __attribute__((ext_vector_type(8)));
typedef h16 h16x4 __attribute__((ext_vector_type(4)));
typedef float f32x4 __attribute__((ext_vector_type(4)));

#define S_LEN 2048
#define QLR   1536
#define KVLR  512
#define NHEAD 16
#define QHD   192
#define QHS   200   // padded row stride for Qh/Kh
#define VDIM  128
#define SCALE 0.07216878364870322f   // 192^-0.5
#define FREQC (-0.4152410118609203f) // -log2(10000)/32

__device__ __forceinline__ void gld16(const h16* g, h16* l){
  __builtin_amdgcn_global_load_lds((__attribute__((address_space(1))) const void*)g,
                                   (__attribute__((address_space(3))) void*)l, 16, 0, 0);
}

// ---------- merged preprocessing: fp32->fp16 cvt + 5 weight transposes ----------
__global__ __launch_bounds__(256) void k_prep(const float* __restrict__ hidden, h16* __restrict__ hb,
      const float* __restrict__ Wqa, const float* __restrict__ Wkva, const float* __restrict__ Wqb,
      const float* __restrict__ Wkvb, const float* __restrict__ Wo,
      h16* __restrict__ Wc, h16* __restrict__ WqbT, h16* __restrict__ WkvbT, h16* __restrict__ WoT){
  int bx = blockIdx.x;
  const int tid = threadIdx.x;
  if (bx < 4096){
    int i = bx*256 + tid;
    float4 v = ((const float4*)hidden)[i];
    h16x4 o = { (h16)v.x, (h16)v.y, (h16)v.z, (h16)v.w };
    ((h16x4*)hb)[i] = o;
    return;
  }
  bx -= 4096;
  const float* W; h16* WT; int K, N, nx;
  if (bx < 768)       { W = Wqa;  WT = Wc;                K = 2048; N = 1536; nx = 24; }
  else if (bx < 1056) { bx -= 768;  W = Wkva; WT = Wc + 1536ull*2048; K = 2048; N = 576;  nx = 9;  }
  else if (bx < 2208) { bx -= 1056; W = Wqb;  WT = WqbT;  K = 1536; N = 3072; nx = 48; }
  else if (bx < 2720) { bx -= 2208; W = Wkvb; WT = WkvbT; K = 512;  N = 4096; nx = 64; }
  else                { bx -= 2720; W = Wo;   WT = WoT;   K = 2048; N = 2048; nx = 32; }
  int ty = bx / nx, tx = bx - ty*nx;
  int k0 = ty * 64, n0 = tx * 64;
  __shared__ float t[64][65];
  int r = tid >> 4, c4 = (tid & 15) * 4;
#pragma unroll
  for (int it = 0; it < 4; it++){
    float4 v = *(const float4*)(W + (size_t)(k0 + it*16 + r) * N + n0 + c4);
    t[it*16+r][c4] = v.x; t[it*16+r][c4+1] = v.y; t[it*16+r][c4+2] = v.z; t[it*16+r][c4+3] = v.w;
  }
  __syncthreads();
  int n = tid >> 2, k16 = (tid & 3) * 16;
  h16x8 o0, o1;
#pragma unroll
  for (int e = 0; e < 8; e++){ o0[e] = (h16)t[k16 + e][n]; o1[e] = (h16)t[k16 + 8 + e][n]; }
  h16* dst = WT + (size_t)(n0 + n) * K + k0 + k16;
  *(h16x8*)dst = o0;
  *(h16x8*)(dst + 8) = o1;
}

// ---------- shared GEMM mainloop (MB = 64 or 128 row tile) ----------
template<int MB>
__device__ __forceinline__ void gemm_coreT(const h16* __restrict__ A, const h16* __restrict__ B,
    int K, int m0, int n0, h16* As, h16* Bs, f32x4 (&acc)[MB/32][4]){
  const int tid = threadIdx.x;
  const int lane = tid & 63, quad = lane >> 4, lr = lane & 15;
  const int wid = tid >> 6;
  const int wr = (wid >> 1) * (MB/2), wc = (wid & 1) * 64;
  const int sr = tid >> 2, scc = (tid & 3) * 8;
  const h16* Ag = A + (size_t)(m0 + sr) * K + scc;
  const h16* Bg = B + (size_t)(n0 + sr) * K + scc;
  for (int kt = 0; kt < K; kt += 32){
    gld16(Ag + kt, &As[tid * 8]);
    if (MB == 128) gld16(Ag + (size_t)64*K + kt, &As[2048 + tid * 8]);
    gld16(Bg + kt,                 &Bs[tid * 8]);
    gld16(Bg + (size_t)64*K + kt,  &Bs[2048 + tid * 8]);
    __syncthreads();
    h16x8 af[MB/32], bfr[4];
#pragma unroll
    for (int r = 0; r < MB/32; r++) af[r] = *(const h16x8*)&As[(wr + r*16 + lr) * 32 + quad * 8];
#pragma unroll
    for (int c = 0; c < 4; c++) bfr[c] = *(const h16x8*)&Bs[(wc + c*16 + lr) * 32 + quad * 8];
#pragma unroll
    for (int r = 0; r < MB/32; r++)
#pragma unroll
      for (int c = 0; c < 4; c++)
        acc[r][c] = __builtin_amdgcn_mfma_f32_16x16x32_f16(af[r], bfr[c], acc[r][c], 0, 0, 0);
    __syncthreads();
  }
}

// ---------- plain GEMM ----------
template<bool OF32, int MB>
__global__ __launch_bounds__(256) void k_gemm(const h16* __restrict__ A, const h16* __restrict__ B,
                                              void* __restrict__ Cv, int N, int K){
  __shared__ __attribute__((aligned(16))) h16 As[MB*32];
  __shared__ __attribute__((aligned(16))) h16 Bs[128*32];
  const int m0 = blockIdx.y * MB, n0 = blockIdx.x * 128;
  f32x4 acc[MB/32][4] = {};
  gemm_coreT<MB>(A, B, K, m0, n0, As, Bs, acc);
  const int lane = threadIdx.x & 63, quad = lane >> 4, lr = lane & 15;
  const int wid = threadIdx.x >> 6;
  const int wr = (wid >> 1) * (MB/2), wc = (wid & 1) * 64;
#pragma unroll
  for (int r = 0; r < MB/32; r++)
#pragma unroll
    for (int c = 0; c < 4; c++){
      int row = m0 + wr + r*16 + quad*4;
      int col = n0 + wc + c*16 + lr;
#pragma unroll
      for (int i = 0; i < 4; i++){
        float val = acc[r][c][i];
        if (OF32) ((float*)Cv)[(size_t)(row + i) * N + col] = val;
        else      ((h16*)Cv)[(size_t)(row + i) * N + col] = (h16)val;
      }
    }
}

// ---------- merged Q + KV GEMM (union LDS: tsm aliases As/Bs) ----------
__global__ __launch_bounds__(256) void k_gemm_qkv(const h16* __restrict__ qln, const h16* __restrict__ WqbT,
      const h16* __restrict__ kvln, const h16* __restrict__ WkvbT,
      h16* __restrict__ Qh, h16* __restrict__ Kh, h16* __restrict__ VT,
      const float* __restrict__ cst, const float* __restrict__ snt){
  __shared__ __attribute__((aligned(16))) h16 smem[16896];   // 33792 B: max(As+Bs, tsm)
  h16* As = smem;
  h16* Bs = smem + 4096;
  const int m0 = blockIdx.y * 128;
  const int tid = threadIdx.x;
  const int lane = tid & 63, quad = lane >> 4, lr = lane & 15;
  const int wid = tid >> 6;
  const int wr = (wid >> 1) * 64, wc = (wid & 1) * 64;
  f32x4 acc[4][4] = {};
  if (blockIdx.x < 24){
    // ---- Q path: qln x WqbT with scale/RoPE epilogue -> Qh (stride 200) ----
    const int n0 = blockIdx.x * 128;
    gemm_coreT<128>(qln, WqbT, QLR, m0, n0, As, Bs, acc);
#pragma unroll
    for (int r = 0; r < 4; r++)
#pragma unroll
      for (int c = 0; c < 4; c++){
        int row0 = m0 + wr + r*16 + quad*4;
        int cg = n0 + wc + c*16 + lr;
        int head = cg / 192;
        int inner = cg - head*192;
        h16* outb = Qh + ((size_t)head*S_LEN)*QHS;
        if (inner < 128){
#pragma unroll
          for (int i = 0; i < 4; i++)
            outb[(size_t)(row0+i)*QHS + inner] = (h16)(acc[r][c][i] * SCALE);
        } else {
          int d = (inner - 128) >> 1;
          int isY = inner & 1;
          int ocol = (isY ? 160 : 128) + d;
#pragma unroll
          for (int i = 0; i < 4; i++){
            int rr = row0 + i;
            float cs = cst[rr*32 + d], sn = snt[rr*32 + d];
            float v = acc[r][c][i];
            float w = __shfl_xor(v, 1);
            float out = isY ? (v*cs + w*sn) : (v*cs - w*sn);
            outb[(size_t)rr*QHS + ocol] = (h16)(out * SCALE);
          }
        }
      }
  } else {
    // ---- KV path: kvln x WkvbT -> Kh nope (stride 200) / VT (rotated, transposed-store) ----
    const int n0 = (blockIdx.x - 24) * 128;
    gemm_coreT<128>(kvln, WkvbT, KVLR, m0, n0, As, Bs, acc);
    const int head = n0 >> 8;
    if ((n0 & 128) == 0){
#pragma unroll
      for (int r = 0; r < 4; r++)
#pragma unroll
        for (int c = 0; c < 4; c++){
          int row0 = m0 + wr + r*16 + quad*4;
          int inner = wc + c*16 + lr;
#pragma unroll
          for (int i = 0; i < 4; i++)
            Kh[((size_t)head*S_LEN + row0 + i)*QHS + inner] = (h16)acc[r][c][i];
        }
    } else {
      // store TRANSPOSED into tsm[dv][row] (stride 132) with h16x4 vector writes
      h16* tsm = smem;   // aliases As/Bs (dead after gemm_coreT's final barrier)
#pragma unroll
      for (int r = 0; r < 4; r++)
#pragma unroll
        for (int c = 0; c < 4; c++){
          int dv = wc + c*16 + lr;
          int row0 = wr + r*16 + quad*4;
          h16x4 o = { (h16)acc[r][c][0], (h16)acc[r][c][1], (h16)acc[r][c][2], (h16)acc[r][c][3] };
          *(h16x4*)&tsm[dv*132 + row0] = o;
        }
      __syncthreads();
      int dv = tid >> 1, half = tid & 1;
      h16* vout = VT + ((size_t)(head*VDIM + dv))*S_LEN + m0 + half*64;
#pragma unroll
      for (int k = 0; k < 8; k++){
        h16x4 a = *(const h16x4*)&tsm[dv*132 + half*64 + k*8];
        h16x4 b = *(const h16x4*)&tsm[dv*132 + half*64 + k*8 + 4];
        h16x8 v = { a[0],a[1],a[2],a[3], b[0],b[1],b[2],b[3] };
        *(h16x8*)(vout + ((k*8 + 8*(dv & 7)) & 63)) = v;
      }
    }
  }
}

// ---------- RMSNorm + k_pe RoPE (writes Kh rope cols for all heads) + cos/sin tables ----------
__global__ __launch_bounds__(256) void k_norm(const h16* __restrict__ Cc,
      const float* __restrict__ qw, const float* __restrict__ kw, const int* __restrict__ pos_ids,
      h16* __restrict__ qln, h16* __restrict__ kvln, h16* __restrict__ Kh,
      float* __restrict__ cst, float* __restrict__ snt){
  const int s = blockIdx.x, tid = threadIdx.x;
  __shared__ float red[8];
  __shared__ h16 kpe_s[64];
  const h16* c1 = Cc + (size_t)s * 2176;
  float v[6]; float ss = 0.f;
#pragma unroll
  for (int i = 0; i < 6; i++){ v[i] = (float)c1[tid + i*256]; ss += v[i]*v[i]; }
  for (int off = 32; off > 0; off >>= 1) ss += __shfl_down(ss, off);
  if ((tid & 63) == 0) red[tid >> 6] = ss;
  __syncthreads();
  float rq = rsqrtf((red[0]+red[1]+red[2]+red[3]) / (float)QLR + 1e-6f);
#pragma unroll
  for (int i = 0; i < 6; i++)
    qln[(size_t)s * QLR + tid + i*256] = (h16)(qw[tid + i*256] * v[i] * rq);

  const h16* ck = c1 + QLR;
  float w0 = (float)ck[tid], w1 = (float)ck[tid + 256];
  float ss2 = w0*w0 + w1*w1;
  for (int off = 32; off > 0; off >>= 1) ss2 += __shfl_down(ss2, off);
  if ((tid & 63) == 0) red[4 + (tid >> 6)] = ss2;
  __syncthreads();
  float rk = rsqrtf((red[4]+red[5]+red[6]+red[7]) / (float)KVLR + 1e-6f);
  kvln[(size_t)s * KVLR + tid]       = (h16)(kw[tid] * w0 * rk);
  kvln[(size_t)s * KVLR + tid + 256] = (h16)(kw[tid + 256] * w1 * rk);

  if (tid < 32){
    int d = tid;
    float x = (float)ck[KVLR + 2*d];
    float y = (float)ck[KVLR + 2*d + 1];
    float a = (float)pos_ids[s] * exp2f(FREQC * (float)d);
    float cs = cosf(a), sn = sinf(a);
    cst[s*32 + d] = cs; snt[s*32 + d] = sn;
    kpe_s[d]      = (h16)(x*cs - y*sn);
    kpe_s[32 + d] = (h16)(y*cs + x*sn);
  }
  __syncthreads();
  {
    int h = tid >> 4, seg = (tid & 15) * 4;
    h16x4 o = { kpe_s[seg], kpe_s[seg+1], kpe_s[seg+2], kpe_s[seg+3] };
    *(h16x4*)&Kh[((size_t)h*S_LEN + s)*QHS + 128 + seg] = o;
  }
}

// ---------- causal flash: BM=128, BKV=64, split-KV <=8, chunked Psm, NO vgpr clamp ----------
// LDS 53248 B -> 3 blocks/CU by LDS; launch_bounds(256,2) keeps VGPR budget (116) spill-free.
__global__ __launch_bounds__(256, 2) void k_flash(const h16* __restrict__ Qh, const h16* __restrict__ Kh,
      const h16* __restrict__ VT, h16* __restrict__ Opart, float* __restrict__ ml){
  const int tile = 15 - blockIdx.x;   // most work first
  const int h = blockIdx.y;
  const int p = blockIdx.z;
  const int jcount = 2*tile + 2;
  const int jlo = p * 8;
  if (jlo >= jcount) return;
  const int jhi = min(jlo + 8, jcount);
  const int m0 = tile * 128;
  __shared__ __attribute__((aligned(16))) h16 Ksm[64*QHS];   // 25600 B
  __shared__ __attribute__((aligned(16))) h16 Vsm[144*64];   // 18432 B, rows 128..143 = ones
  __shared__ __attribute__((aligned(16))) h16 Psm[128*36];   // 9216 B: [128 q][32 kv-chunk + 4 pad]
  const int tid = threadIdx.x, wid = tid >> 6, lane = tid & 63, quad = lane >> 4, lr = lane & 15;

  {
    h16x4 one4 = { (h16)1.f, (h16)1.f, (h16)1.f, (h16)1.f };
    *(h16x4*)&Vsm[128*64 + tid*4] = one4;
  }

  // Q fragments direct from global (once per block)
  const h16* Qbase = Qh + ((size_t)h*S_LEN + m0)*QHS;
  h16x8 qf[2][6];
#pragma unroll
  for (int rt = 0; rt < 2; rt++)
#pragma unroll
    for (int ks = 0; ks < 6; ks++)
      qf[rt][ks] = *(const h16x8*)(Qbase + (size_t)(wid*32 + rt*16 + lr)*QHS + ks*32 + quad*8);

  float mst[2][4];
  f32x4 oacc[2][9] = {};   // 8 V tiles + 1 ones tile (row-sum l)
#pragma unroll
  for (int rt = 0; rt < 2; rt++)
#pragma unroll
    for (int i = 0; i < 4; i++) mst[rt][i] = -1e30f;

  for (int j = jlo; j < jhi; ++j){
    const h16* Kg = Kh + ((size_t)h*S_LEN + j*64)*QHS;
#pragma unroll
    for (int i = 0; i < 6; i++) gld16(Kg + i*2048 + tid*8, &Ksm[i*2048 + tid*8]);
    if (tid < 64) gld16(Kg + 12288 + tid*8, &Ksm[12288 + tid*8]);
    const h16* Vg = VT + (size_t)h * VDIM * S_LEN + (size_t)j * 64;
#pragma unroll
    for (int i = 0; i < 4; i++)
      gld16(Vg + (size_t)(i*32 + (tid >> 3)) * S_LEN + (tid & 7)*8, &Vsm[i*2048 + tid*8]);
    __syncthreads();

    f32x4 sc[2][4] = {};
#pragma unroll
    for (int ks = 0; ks < 6; ks++)
#pragma unroll
      for (int ct = 0; ct < 4; ct++){
        h16x8 kf = *(const h16x8*)&Ksm[(ct*16 + lr)*QHS + ks*32 + quad*8];
        sc[0][ct] = __builtin_amdgcn_mfma_f32_16x16x32_f16(qf[0][ks], kf, sc[0][ct], 0,0,0);
        sc[1][ct] = __builtin_amdgcn_mfma_f32_16x16x32_f16(qf[1][ks], kf, sc[1][ct], 0,0,0);
      }

    if (j >= 2*tile){
#pragma unroll
      for (int rt = 0; rt < 2; rt++)
#pragma unroll
        for (int ct = 0; ct < 4; ct++){
          int kcol = j*64 + ct*16 + lr;
#pragma unroll
          for (int i = 0; i < 4; i++)
            if (kcol > m0 + wid*32 + rt*16 + quad*4 + i) sc[rt][ct][i] = -1e30f;
        }
    }

#pragma unroll
    for (int rt = 0; rt < 2; rt++){
      float al[4];
#pragma unroll
      for (int i = 0; i < 4; i++){
        float m = fmaxf(fmaxf(sc[rt][0][i], sc[rt][1][i]), fmaxf(sc[rt][2][i], sc[rt][3][i]));
#pragma unroll
        for (int off = 1; off < 16; off <<= 1) m = fmaxf(m, __shfl_xor(m, off));
        // floor guard: fully-masked rows must yield P=0, not exp(0)=1
        float mn = fmaxf(fmaxf(mst[rt][i], m), -1e29f);
        al[i] = __expf(mst[rt][i] - mn);
        mst[rt][i] = mn;
      }
#pragma unroll
      for (int oc = 0; oc < 9; oc++)
#pragma unroll
        for (int i = 0; i < 4; i++) oacc[rt][oc][i] *= al[i];
    }

    // PV in two 32-kv chunks through small Psm (per-wave rows; in-order DS pipe, no barrier)
#pragma unroll
    for (int c2 = 0; c2 < 2; c2++){
#pragma unroll
      for (int rt = 0; rt < 2; rt++)
#pragma unroll
        for (int cc = 0; cc < 2; cc++){
          int ct = c2*2 + cc;
#pragma unroll
          for (int i = 0; i < 4; i++)
            Psm[(wid*32 + rt*16 + quad*4 + i)*36 + cc*16 + lr] = (h16)__expf(sc[rt][ct][i] - mst[rt][i]);
        }
      h16x8 pf0 = *(const h16x8*)&Psm[(wid*32 + lr)*36      + quad*8];
      h16x8 pf1 = *(const h16x8*)&Psm[(wid*32 + 16 + lr)*36 + quad*8];
      int cv = (c2*32 + quad*8 + 8*(lr & 7)) & 63;
#pragma unroll
      for (int oc = 0; oc < 9; oc++){
        h16x8 vf = *(const h16x8*)&Vsm[(oc*16 + lr)*64 + cv];
        oacc[0][oc] = __builtin_amdgcn_mfma_f32_16x16x32_f16(pf0, vf, oacc[0][oc], 0,0,0);
        oacc[1][oc] = __builtin_amdgcn_mfma_f32_16x16x32_f16(pf1, vf, oacc[1][oc], 0,0,0);
      }
    }
    __syncthreads();
  }

  const int part = (tile*NHEAD + h)*4 + p;
  h16* Op = Opart + (size_t)part * 16384;
#pragma unroll
  for (int rt = 0; rt < 2; rt++){
#pragma unroll
    for (int oc = 0; oc < 8; oc++)
#pragma unroll
      for (int i = 0; i < 4; i++)
        Op[(wid*32 + rt*16 + quad*4 + i)*128 + oc*16 + lr] = (h16)oacc[rt][oc][i];
    if (lr == 0){
#pragma unroll
      for (int i = 0; i < 4; i++){
        int r = wid*32 + rt*16 + quad*4 + i;
        ml[(size_t)part*256 + r*2]     = mst[rt][i];
        ml[(size_t)part*256 + r*2 + 1] = oacc[rt][8][i];
      }
    }
  }
}

// ---------- LSE-combine partials -> Ob ----------
__global__ __launch_bounds__(256) void k_comb(const h16* __restrict__ Opart, const float* __restrict__ ml,
                                              h16* __restrict__ Ob){
  const int t = blockIdx.x, h = blockIdx.y, tid = threadIdx.x;
  const int P = (2*t + 9) >> 3;   // ceil((2t+2)/8)
  const int r = tid >> 1, c0 = (tid & 1) * 64;
  const int base = (t*NHEAD + h)*4;
  float w[4]; float M = -1e30f, denom = 0.f;
  for (int p = 0; p < P; p++) M = fmaxf(M, ml[(size_t)(base+p)*256 + r*2]);
  for (int p = 0; p < P; p++){
    w[p] = __expf(ml[(size_t)(base+p)*256 + r*2] - M);
    denom += w[p] * ml[(size_t)(base+p)*256 + r*2 + 1];
  }
  float inv = 1.f / denom;
#pragma unroll
  for (int ch = 0; ch < 8; ch++){
    float a[8] = {};
    for (int p = 0; p < P; p++){
      h16x8 v = *(const h16x8*)&Opart[(size_t)(base+p)*16384 + r*128 + c0 + ch*8];
#pragma unroll
      for (int e = 0; e < 8; e++) a[e] += w[p] * (float)v[e];
    }
    h16x8 o;
#pragma unroll
    for (int e = 0; e < 8; e++) o[e] = (h16)(a[e] * inv);
    *(h16x8*)&Ob[((size_t)(t*128 + r))*(NHEAD*VDIM) + h*VDIM + c0 + ch*8] = o;
  }
}

extern "C" void kernel_launch(void* const* d_in, const int* in_sizes, int n_in,
                              void* d_out, int out_size, void* d_ws, size_t ws_size,
                              hipStream_t stream){
  const float* hidden = (const float*)d_in[0];
  const int*   pos    = (const int*)  d_in[1];
  const float* Wqa    = (const float*)d_in[2];
  const float* qaw    = (const float*)d_in[3];
  const float* Wqb    = (const float*)d_in[4];
  const float* Wkva   = (const float*)d_in[5];
  const float* kvw    = (const float*)d_in[6];
  const float* Wkvb   = (const float*)d_in[7];
  const float* Wo     = (const float*)d_in[8];

  h16* ws = (h16*)d_ws;
  size_t off = 0;
  auto take = [&](size_t n){ h16* p = ws + off; off += n; return p; };
  h16* hb    = take(2048ull * 2048);
  h16* WoT   = take(2048ull * 2048);
  h16* Wc    = take(2176ull * 2048);   // alias region start (dead before flash)
  h16* WqbT  = take(3072ull * 1536);
  h16* WkvbT = take(4096ull * 512);
  h16* Ccomb = take(2048ull * 2176);
  h16* qln   = take(2048ull * 1536);
  h16* kvln  = take(2048ull * 512);    // alias region end
  float* cst = (float*)take(2048ull * 64);
  float* snt = (float*)take(2048ull * 64);
  h16* Qh    = take(16ull * 2048 * QHS);
  h16* Kh    = take(16ull * 2048 * QHS);
  h16* VT    = take(16ull * 128 * 2048);
  h16* Ob    = hb;                      // hb dead after Ccomb GEMM
  h16*   Opart = Wc;                    // 16*16*4*16384 h16 = 33.6 MB within 39.8 MB region
  float* mlbuf = (float*)(Wc + 16ull*16*4*16384);  // +0.5 MB, inside dead region

  k_prep<<<7840, 256, 0, stream>>>(hidden, hb, Wqa, Wkva, Wqb, Wkvb, Wo, Wc, WqbT, WkvbT, WoT);
  k_gemm<false,64><<<dim3(17, 32), 256, 0, stream>>>(hb, Wc, Ccomb, 2176, 2048);
  k_norm<<<2048, 256, 0, stream>>>(Ccomb, qaw, kvw, pos, qln, kvln, Kh, cst, snt);
  k_gemm_qkv<<<dim3(56, 16), 256, 0, stream>>>(qln, WqbT, kvln, WkvbT, Qh, Kh, VT, cst, snt);
  k_flash<<<dim3(16, 16, 4), 256, 0, stream>>>(Qh, Kh, VT, Opart, mlbuf);
  k_comb<<<dim3(16, 16), 256, 0, stream>>>(Opart, mlbuf, Ob);
  k_gemm<true,64><<<dim3(16, 32), 256, 0, stream>>>(Ob, WoT, d_out, 2048, 2048);
}